// Round 8
// baseline (36.245 us; speedup 1.0000x reference)
//
#include <hip/hip_runtime.h>

typedef float f2 __attribute__((ext_vector_type(2)));

#define N_QUBITS 5
#define DIM 32
#define N_LAYERS 2

// CNOT permutation: new[i] = old[i ^ (cbit << pos_t)]
__host__ __device__ constexpr int cnot_apply(int i, int ctrl, int tgt) {
    const int pc = N_QUBITS - 1 - ctrl;
    const int pt = N_QUBITS - 1 - tgt;
    return i ^ (((i >> pc) & 1) << pt);
}
// Composed CNOT ring of a layer: new[i] = old[layer_perm(i,r)]  [round-1/2/7 verified]
__host__ __device__ constexpr int layer_perm(int i, int r) {
    int idx = i;
    for (int q = N_QUBITS - 1; q >= 0; --q)
        idx = cnot_apply(idx, q, (q + r) % N_QUBITS);
    return idx;
}

// ---- tiny prep kernel: 10 Rot gates -> 4 coeffs each (g11=conj(g00), g10=-conj(g01))
__global__ void vqc_prep(const float* __restrict__ w, float* __restrict__ coef)
{
    const int t = threadIdx.x;
    if (t < N_LAYERS * N_QUBITS) {
        const float phi = w[t * 3 + 0];
        const float th  = w[t * 3 + 1];
        const float om  = w[t * 3 + 2];
        float s, c;   sincosf(0.5f * th, &s, &c);
        float sp, cp; sincosf(0.5f * (phi + om), &sp, &cp);
        float sm, cm; sincosf(0.5f * (phi - om), &sm, &cm);
        coef[t * 4 + 0] =  cp * c;   // g00r
        coef[t * 4 + 1] = -sp * c;   // g00i
        coef[t * 4 + 2] = -cm * s;   // g01r
        coef[t * 4 + 3] = -sm * s;   // g01i
    }
}

// ---- main kernel: no LDS, no syncthreads; consts via wave-uniform s_loads ----
__global__ __launch_bounds__(256, 3) void vqc_main(
    const float* __restrict__ x,      // (B, 5)
    const float* __restrict__ coef,   // (10, 4) from prep
    const float* __restrict__ fc_w,   // (8, 5)
    const float* __restrict__ fc_b,   // (8,)
    float* __restrict__ out,          // (B, 8)
    int Btot)
{
    const int b = blockIdx.x * 256 + threadIdx.x;
    if (b >= Btot) return;

    // ---- RX product state by doubling (round-2 verbatim) ----
    const float* xp = x + (size_t)b * 5;
    f2 st[DIM];
    st[0] = f2{1.f, 0.f};
#pragma unroll
    for (int q = 0; q < N_QUBITS; ++q) {
        float s, c;
        __sincosf(0.5f * xp[q], &s, &c);
        const int stride = 1 << (4 - q);
#pragma unroll
        for (int k = 0; k < (1 << q); ++k) {
            const int m = k * (stride << 1);
            const f2 a = st[m];
            st[m + stride] = f2{s * a.y, -s * a.x};   // -i*s*a
            st[m] = a * c;
        }
    }

    // ---- 2 layers x 5 Rot butterflies; perms folded into compile-time indices ----
    // Layer 0 gates address st directly. After layer 0 the CNOT perm pi1 is NOT
    // applied physically: layer-1 gates address st[pi1(idx)], and the final
    // probability read composes pi1(pi2(i)).  [pi2-fold verified in round 7]
#pragma unroll
    for (int l = 0; l < N_LAYERS; ++l) {
#pragma unroll
        for (int q = 0; q < N_QUBITS; ++q) {
            const int gi = (l * N_QUBITS + q) * 4;
            const float c00r = coef[gi + 0];   // uniform -> SGPR
            const float c00i = coef[gi + 1];
            const float c01r = coef[gi + 2];
            const float c01i = coef[gi + 3];
            const int stride = 1 << (4 - q);
            const int mask = stride - 1;
#pragma unroll
            for (int p = 0; p < DIM / 2; ++p) {
                const int a0 = ((p & ~mask) << 1) | (p & mask);
                const int ia = (l == 0) ? a0 : layer_perm(a0, 1);
                const int ib = (l == 0) ? (a0 + stride) : layer_perm(a0 + stride, 1);
                const float ar = st[ia].x, ai = st[ia].y;
                const float br = st[ib].x, bi = st[ib].y;
                st[ia] = f2{ c00r * ar - c00i * ai + c01r * br - c01i * bi,
                             c00r * ai + c00i * ar + c01r * bi + c01i * br };
                st[ib] = f2{-c01r * ar - c01i * ai + c00r * br + c00i * bi,
                            -c01r * ai + c01i * ar - c00i * br + c00r * bi };
            }
        }
    }

    // ---- probs, both perms folded: final[i] = st[pi1(pi2(i))] ----
    float pr[DIM];
#pragma unroll
    for (int i = 0; i < DIM; ++i) {
        const f2 sv = st[layer_perm(layer_perm(i, 2), 1)];
        pr[i] = sv.x * sv.x + sv.y * sv.y;
    }

    // ---- expvals via Walsh-Hadamard partial-sum tree (round-2 verbatim) ----
    float v16[16], v8[8], v4[4], v2[2];
    float ev4 = 0.f, ev3 = 0.f, ev2 = 0.f, ev1 = 0.f, ev0;
#pragma unroll
    for (int j = 0; j < 16; ++j) { v16[j] = pr[2*j] + pr[2*j+1]; ev4 += pr[2*j] - pr[2*j+1]; }
#pragma unroll
    for (int j = 0; j < 8; ++j)  { v8[j] = v16[2*j] + v16[2*j+1]; ev3 += v16[2*j] - v16[2*j+1]; }
#pragma unroll
    for (int j = 0; j < 4; ++j)  { v4[j] = v8[2*j] + v8[2*j+1];  ev2 += v8[2*j] - v8[2*j+1]; }
#pragma unroll
    for (int j = 0; j < 2; ++j)  { v2[j] = v4[2*j] + v4[2*j+1];  ev1 += v4[2*j] - v4[2*j+1]; }
    ev0 = v2[0] - v2[1];
    const float ev[N_QUBITS] = {ev0, ev1, ev2, ev3, ev4};

    // ---- FC (fc_w/fc_b via uniform s_loads) + coalesced store ----
    float o[8];
#pragma unroll
    for (int j = 0; j < 8; ++j) {
        float acc = fc_b[j];
#pragma unroll
        for (int q = 0; q < 5; ++q) acc += ev[q] * fc_w[j * 5 + q];
        o[j] = acc;
    }
    float4* op = (float4*)(out + (size_t)b * 8);
    op[0] = make_float4(o[0], o[1], o[2], o[3]);
    op[1] = make_float4(o[4], o[5], o[6], o[7]);
}

extern "C" void kernel_launch(void* const* d_in, const int* in_sizes, int n_in,
                              void* d_out, int out_size, void* d_ws, size_t ws_size,
                              hipStream_t stream) {
    const float* x    = (const float*)d_in[0];
    const float* w    = (const float*)d_in[1];
    const float* fc_w = (const float*)d_in[2];
    const float* fc_b = (const float*)d_in[3];
    float* out  = (float*)d_out;
    float* coef = (float*)d_ws;                    // 40 floats

    const int Btot = in_sizes[0] / N_QUBITS;       // 262144
    hipLaunchKernelGGL(vqc_prep, dim3(1), dim3(64), 0, stream, w, coef);
    const int grid = (Btot + 255) / 256;
    hipLaunchKernelGGL(vqc_main, dim3(grid), dim3(256), 0, stream,
                       x, coef, fc_w, fc_b, out, Btot);
}

// Round 9
// 18.105 us; speedup vs baseline: 2.0019x; 2.0019x over previous
//
#include <hip/hip_runtime.h>

typedef float f2 __attribute__((ext_vector_type(2)));

#define N_QUBITS 5
#define DIM 32
#define N_LAYERS 2

// CNOT permutation: new[i] = old[i ^ (cbit << pos_t)]
__host__ __device__ constexpr int cnot_apply(int i, int ctrl, int tgt) {
    const int pc = N_QUBITS - 1 - ctrl;
    const int pt = N_QUBITS - 1 - tgt;
    return i ^ (((i >> pc) & 1) << pt);
}
// Composed CNOT ring of a layer: new[i] = old[layer_perm(i,r)]  [rounds 1/2/7/8 verified]
__host__ __device__ constexpr int layer_perm(int i, int r) {
    int idx = i;
    for (int q = N_QUBITS - 1; q >= 0; --q)
        idx = cnot_apply(idx, q, (q + r) % N_QUBITS);
    return idx;
}

__device__ inline f2 cmul(f2 a, f2 b) {
    return f2{a.x * b.x - a.y * b.y, a.x * b.y + a.y * b.x};
}

__global__ __launch_bounds__(256, 3) void vqc_kernel(
    const float* __restrict__ x,      // (B, 5)
    const float* __restrict__ w,      // (2, 5, 3)
    const float* __restrict__ fc_w,   // (8, 5)
    const float* __restrict__ fc_b,   // (8,)
    float* __restrict__ out,          // (B, 8)
    int Btot)
{
    // ---- block-uniform gate precompute (round 2/7 style) ----
    // layer 0: raw 8 coeffs per qubit (folded per-thread with RX below)
    // layer 1: packed P,Q,R,S per qubit (round-2 butterfly form)
    __shared__ float s_g0[N_QUBITS][8];
    __shared__ f2    s_g1[N_QUBITS][4];
    __shared__ float s_fc_w[40];
    __shared__ float s_fc_b[8];

    const int t = threadIdx.x;
    if (t < N_LAYERS * N_QUBITS) {
        const float phi = w[t * 3 + 0];
        const float th  = w[t * 3 + 1];
        const float om  = w[t * 3 + 2];
        float s, c;   sincosf(0.5f * th, &s, &c);
        float sp, cp; sincosf(0.5f * (phi + om), &sp, &cp);
        float sm, cm; sincosf(0.5f * (phi - om), &sm, &cm);
        const float g00r =  cp * c, g00i = -sp * c;
        const float g01r = -cm * s, g01i = -sm * s;
        const float g10r =  cm * s, g10i = -sm * s;
        const float g11r =  cp * c, g11i =  sp * c;
        if (t < N_QUBITS) {           // layer 0, raw
            s_g0[t][0] = g00r; s_g0[t][1] = g00i;
            s_g0[t][2] = g01r; s_g0[t][3] = g01i;
            s_g0[t][4] = g10r; s_g0[t][5] = g10i;
            s_g0[t][6] = g11r; s_g0[t][7] = g11i;
        } else {                      // layer 1, packed
            const int q = t - N_QUBITS;
            s_g1[q][0] = f2{ g00r,  g00r};
            s_g1[q][1] = f2{-g00i,  g00i};
            s_g1[q][2] = f2{ g01r,  g01r};
            s_g1[q][3] = f2{-g01i,  g01i};
        }
    } else if (t >= 16 && t < 56) {
        s_fc_w[t - 16] = fc_w[t - 16];
    } else if (t >= 56 && t < 64) {
        s_fc_b[t - 56] = fc_b[t - 56];
    }
    __syncthreads();

    const int b = blockIdx.x * 256 + t;
    if (b >= Btot) return;

    const float* xp = x + (size_t)b * 5;

    // ---- product state after layer 0: st = ⊗_q (Rot0_q · RX(x_q) |0>) ----
    // v computed INLINE per qubit (no arrays -> no live-range blowup, cf. round 7).
    // v0 = g00*c + g01*(-is) ; v1 = g10*c + g11*(-is)   [round-7-verified formulas]
    f2 st[DIM];
    {
        float s, c;
        __sincosf(0.5f * xp[0], &s, &c);
        st[0]  = f2{s_g0[0][0] * c + s_g0[0][3] * s, s_g0[0][1] * c - s_g0[0][2] * s};
        st[16] = f2{s_g0[0][4] * c + s_g0[0][7] * s, s_g0[0][5] * c - s_g0[0][6] * s};
    }
#pragma unroll
    for (int q = 1; q < N_QUBITS; ++q) {
        float s, c;
        __sincosf(0.5f * xp[q], &s, &c);
        const f2 v0 = f2{s_g0[q][0] * c + s_g0[q][3] * s, s_g0[q][1] * c - s_g0[q][2] * s};
        const f2 v1 = f2{s_g0[q][4] * c + s_g0[q][7] * s, s_g0[q][5] * c - s_g0[q][6] * s};
        const int stride = 1 << (4 - q);
#pragma unroll
        for (int k = 0; k < (1 << q); ++k) {
            const int m = k * (stride << 1);
            const f2 a = st[m];
            st[m + stride] = cmul(v1, a);
            st[m]          = cmul(v0, a);
        }
    }

    // ---- layer 1: 5 packed Rot butterflies on pi1-composed indices ----
    // (packed butterfly round-2-verified; index composition round-8-verified)
#pragma unroll
    for (int q = 0; q < N_QUBITS; ++q) {
        const f2 P = s_g1[q][0], Q = s_g1[q][1];
        const f2 R = s_g1[q][2], S = s_g1[q][3];
        const int stride = 1 << (4 - q);
        const int mask = stride - 1;
#pragma unroll
        for (int p = 0; p < DIM / 2; ++p) {
            const int a0 = ((p & ~mask) << 1) | (p & mask);
            const int ia = layer_perm(a0, 1);
            const int ib = layer_perm(a0 + stride, 1);
            const f2 a = st[ia], bb = st[ib];
            const f2 as = f2{a.y, a.x};
            const f2 bs = f2{bb.y, bb.x};
            st[ia] = P * a + Q * as + R * bb + S * bs;
            st[ib] = P * bb + S * as - R * a - Q * bs;
        }
    }

    // ---- probs, both perms folded: final[i] = st[pi1(pi2(i))]  [round-8-verified] ----
    float pr[DIM];
#pragma unroll
    for (int i = 0; i < DIM; ++i) {
        const f2 sv = st[layer_perm(layer_perm(i, 2), 1)];
        pr[i] = sv.x * sv.x + sv.y * sv.y;
    }

    // ---- expvals via Walsh-Hadamard partial-sum tree (round-2 verbatim) ----
    float v16[16], v8[8], v4[4], v2[2];
    float ev4 = 0.f, ev3 = 0.f, ev2 = 0.f, ev1 = 0.f, ev0;
#pragma unroll
    for (int j = 0; j < 16; ++j) { v16[j] = pr[2*j] + pr[2*j+1]; ev4 += pr[2*j] - pr[2*j+1]; }
#pragma unroll
    for (int j = 0; j < 8; ++j)  { v8[j] = v16[2*j] + v16[2*j+1]; ev3 += v16[2*j] - v16[2*j+1]; }
#pragma unroll
    for (int j = 0; j < 4; ++j)  { v4[j] = v8[2*j] + v8[2*j+1];  ev2 += v8[2*j] - v8[2*j+1]; }
#pragma unroll
    for (int j = 0; j < 2; ++j)  { v2[j] = v4[2*j] + v4[2*j+1];  ev1 += v4[2*j] - v4[2*j+1]; }
    ev0 = v2[0] - v2[1];
    const float ev[N_QUBITS] = {ev0, ev1, ev2, ev3, ev4};

    // ---- FC: out[b,j] = sum_q ev[q]*fc_w[j,q] + fc_b[j] ----
    float o[8];
#pragma unroll
    for (int j = 0; j < 8; ++j) {
        float acc = s_fc_b[j];
#pragma unroll
        for (int q = 0; q < 5; ++q) acc += ev[q] * s_fc_w[j * 5 + q];
        o[j] = acc;
    }
    float4* op = (float4*)(out + (size_t)b * 8);
    op[0] = make_float4(o[0], o[1], o[2], o[3]);
    op[1] = make_float4(o[4], o[5], o[6], o[7]);
}

extern "C" void kernel_launch(void* const* d_in, const int* in_sizes, int n_in,
                              void* d_out, int out_size, void* d_ws, size_t ws_size,
                              hipStream_t stream) {
    const float* x    = (const float*)d_in[0];
    const float* w    = (const float*)d_in[1];
    const float* fc_w = (const float*)d_in[2];
    const float* fc_b = (const float*)d_in[3];
    float* out = (float*)d_out;

    const int Btot = in_sizes[0] / N_QUBITS;   // 262144
    const int grid = (Btot + 255) / 256;
    hipLaunchKernelGGL(vqc_kernel, dim3(grid), dim3(256), 0, stream,
                       x, w, fc_w, fc_b, out, Btot);
}

// Round 10
// 15.920 us; speedup vs baseline: 2.2767x; 1.1373x over previous
//
#include <hip/hip_runtime.h>

typedef float f2 __attribute__((ext_vector_type(2)));

#define N_QUBITS 5
#define DIM 32
#define N_LAYERS 2

// CNOT permutation: new[i] = old[i ^ (cbit << pos_t)]
__host__ __device__ constexpr int cnot_apply(int i, int ctrl, int tgt) {
    const int pc = N_QUBITS - 1 - ctrl;
    const int pt = N_QUBITS - 1 - tgt;
    return i ^ (((i >> pc) & 1) << pt);
}
// Composed CNOT ring of a layer: new[i] = old[layer_perm(i,r)]  [rounds 1/2/7/8/9 verified]
__host__ __device__ constexpr int layer_perm(int i, int r) {
    int idx = i;
    for (int q = N_QUBITS - 1; q >= 0; --q)
        idx = cnot_apply(idx, q, (q + r) % N_QUBITS);
    return idx;
}

// SoA over two batches: every f2 holds (value for b0, value for b1).
// State = sre[32], sim[32]. All complex arithmetic is swizzle-free pk ops.
__global__ __launch_bounds__(256, 2) void vqc_kernel(
    const float* __restrict__ x,      // (B, 5)
    const float* __restrict__ w,      // (2, 5, 3)
    const float* __restrict__ fc_w,   // (8, 5)
    const float* __restrict__ fc_b,   // (8,)
    float* __restrict__ out,          // (B, 8)
    int Btot)
{
    // ---- block-uniform gate precompute (round-9 preamble, raw coeffs only) ----
    __shared__ float s_g0[N_QUBITS][8];   // layer 0: 8 raw coeffs
    __shared__ float s_g1[N_QUBITS][4];   // layer 1: c00r,c00i,c01r,c01i
    __shared__ float s_fc_w[40];
    __shared__ float s_fc_b[8];

    const int t = threadIdx.x;
    if (t < N_LAYERS * N_QUBITS) {
        const float phi = w[t * 3 + 0];
        const float th  = w[t * 3 + 1];
        const float om  = w[t * 3 + 2];
        float s, c;   sincosf(0.5f * th, &s, &c);
        float sp, cp; sincosf(0.5f * (phi + om), &sp, &cp);
        float sm, cm; sincosf(0.5f * (phi - om), &sm, &cm);
        const float g00r =  cp * c, g00i = -sp * c;
        const float g01r = -cm * s, g01i = -sm * s;
        const float g10r =  cm * s, g10i = -sm * s;
        const float g11r =  cp * c, g11i =  sp * c;
        if (t < N_QUBITS) {           // layer 0, raw
            s_g0[t][0] = g00r; s_g0[t][1] = g00i;
            s_g0[t][2] = g01r; s_g0[t][3] = g01i;
            s_g0[t][4] = g10r; s_g0[t][5] = g10i;
            s_g0[t][6] = g11r; s_g0[t][7] = g11i;
        } else {                      // layer 1, raw (g10/g11 derived: conj relations)
            const int q = t - N_QUBITS;
            s_g1[q][0] = g00r; s_g1[q][1] = g00i;
            s_g1[q][2] = g01r; s_g1[q][3] = g01i;
        }
    } else if (t >= 16 && t < 56) {
        s_fc_w[t - 16] = fc_w[t - 16];
    } else if (t >= 56 && t < 64) {
        s_fc_b[t - 56] = fc_b[t - 56];
    }
    __syncthreads();

    const int b0 = blockIdx.x * 512 + t;
    if (b0 >= Btot) return;
    const int b1 = b0 + 256;
    const int b1c = (b1 < Btot) ? b1 : b0;        // clamp for loads only

    const float* xp0 = x + (size_t)b0 * 5;
    const float* xp1 = x + (size_t)b1c * 5;

    // ---- product state after layer 0: st = ⊗_q (Rot0_q · RX(x_q)|0>) ----
    // v formulas round-7/9-verified, componentized per (re,im) in SoA form.
    f2 sre[DIM], sim[DIM];
    {
        float s0, c0, s1, c1;
        __sincosf(0.5f * xp0[0], &s0, &c0);
        __sincosf(0.5f * xp1[0], &s1, &c1);
        const f2 cc = f2{c0, c1}, ss = f2{s0, s1};
        sre[0]  = s_g0[0][0] * cc + s_g0[0][3] * ss;
        sim[0]  = s_g0[0][1] * cc - s_g0[0][2] * ss;
        sre[16] = s_g0[0][4] * cc + s_g0[0][7] * ss;
        sim[16] = s_g0[0][5] * cc - s_g0[0][6] * ss;
    }
#pragma unroll
    for (int q = 1; q < N_QUBITS; ++q) {
        float s0, c0, s1, c1;
        __sincosf(0.5f * xp0[q], &s0, &c0);
        __sincosf(0.5f * xp1[q], &s1, &c1);
        const f2 cc = f2{c0, c1}, ss = f2{s0, s1};
        const f2 v0re = s_g0[q][0] * cc + s_g0[q][3] * ss;
        const f2 v0im = s_g0[q][1] * cc - s_g0[q][2] * ss;
        const f2 v1re = s_g0[q][4] * cc + s_g0[q][7] * ss;
        const f2 v1im = s_g0[q][5] * cc - s_g0[q][6] * ss;
        const int stride = 1 << (4 - q);
#pragma unroll
        for (int k = 0; k < (1 << q); ++k) {
            const int m = k * (stride << 1);
            const f2 are = sre[m], aim = sim[m];
            sre[m + stride] = v1re * are - v1im * aim;   // cmul(v1, a), SoA
            sim[m + stride] = v1re * aim + v1im * are;
            sre[m]          = v0re * are - v0im * aim;   // cmul(v0, a)
            sim[m]          = v0re * aim + v0im * are;
        }
    }

    // ---- layer 1: 5 Rot butterflies on pi1-composed indices ----
    // scalar formulas round-8-verified; index composition round-8/9-verified.
#pragma unroll
    for (int q = 0; q < N_QUBITS; ++q) {
        const float c00r = s_g1[q][0], c00i = s_g1[q][1];
        const float c01r = s_g1[q][2], c01i = s_g1[q][3];
        const int stride = 1 << (4 - q);
        const int mask = stride - 1;
#pragma unroll
        for (int p = 0; p < DIM / 2; ++p) {
            const int a0 = ((p & ~mask) << 1) | (p & mask);
            const int ia = layer_perm(a0, 1);
            const int ib = layer_perm(a0 + stride, 1);
            const f2 ar = sre[ia], ai = sim[ia];
            const f2 br = sre[ib], bi = sim[ib];
            sre[ia] =  c00r * ar - c00i * ai + c01r * br - c01i * bi;
            sim[ia] =  c00r * ai + c00i * ar + c01r * bi + c01i * br;
            sre[ib] = -c01r * ar - c01i * ai + c00r * br + c00i * bi;
            sim[ib] = -c01r * ai + c01i * ar - c00i * br + c00r * bi;
        }
    }

    // ---- probs, both perms folded: final[i] = st[pi1(pi2(i))]  [round-9-verified] ----
    f2 pr[DIM];
#pragma unroll
    for (int i = 0; i < DIM; ++i) {
        const int j = layer_perm(layer_perm(i, 2), 1);
        pr[i] = sre[j] * sre[j] + sim[j] * sim[j];
    }

    // ---- expvals via Walsh-Hadamard partial-sum tree (round-2 structure, packed) ----
    f2 v16[16], v8_[8], v4_[4], v2_[2];
    f2 ev4 = f2{0.f, 0.f}, ev3 = f2{0.f, 0.f}, ev2 = f2{0.f, 0.f}, ev1 = f2{0.f, 0.f};
#pragma unroll
    for (int j = 0; j < 16; ++j) { v16[j] = pr[2*j] + pr[2*j+1]; ev4 += pr[2*j] - pr[2*j+1]; }
#pragma unroll
    for (int j = 0; j < 8; ++j)  { v8_[j] = v16[2*j] + v16[2*j+1]; ev3 += v16[2*j] - v16[2*j+1]; }
#pragma unroll
    for (int j = 0; j < 4; ++j)  { v4_[j] = v8_[2*j] + v8_[2*j+1]; ev2 += v8_[2*j] - v8_[2*j+1]; }
#pragma unroll
    for (int j = 0; j < 2; ++j)  { v2_[j] = v4_[2*j] + v4_[2*j+1]; ev1 += v4_[2*j] - v4_[2*j+1]; }
    const f2 ev0 = v2_[0] - v2_[1];
    const f2 ev[N_QUBITS] = {ev0, ev1, ev2, ev3, ev4};

    // ---- FC (packed over both batches) ----
    f2 o[8];
#pragma unroll
    for (int j = 0; j < 8; ++j) {
        f2 acc = f2{s_fc_b[j], s_fc_b[j]};
#pragma unroll
        for (int q = 0; q < 5; ++q) acc += ev[q] * s_fc_w[j * 5 + q];
        o[j] = acc;
    }

    // ---- stores: two coalesced float4 pairs ----
    float4* op0 = (float4*)(out + (size_t)b0 * 8);
    op0[0] = make_float4(o[0].x, o[1].x, o[2].x, o[3].x);
    op0[1] = make_float4(o[4].x, o[5].x, o[6].x, o[7].x);
    if (b1 < Btot) {
        float4* op1 = (float4*)(out + (size_t)b1 * 8);
        op1[0] = make_float4(o[0].y, o[1].y, o[2].y, o[3].y);
        op1[1] = make_float4(o[4].y, o[5].y, o[6].y, o[7].y);
    }
}

extern "C" void kernel_launch(void* const* d_in, const int* in_sizes, int n_in,
                              void* d_out, int out_size, void* d_ws, size_t ws_size,
                              hipStream_t stream) {
    const float* x    = (const float*)d_in[0];
    const float* w    = (const float*)d_in[1];
    const float* fc_w = (const float*)d_in[2];
    const float* fc_b = (const float*)d_in[3];
    float* out = (float*)d_out;

    const int Btot = in_sizes[0] / N_QUBITS;   // 262144
    const int grid = (Btot + 511) / 512;       // 2 batches per thread
    hipLaunchKernelGGL(vqc_kernel, dim3(grid), dim3(256), 0, stream,
                       x, w, fc_w, fc_b, out, Btot);
}